// Round 1
// baseline (4691.325 us; speedup 1.0000x reference)
//
#include <hip/hip_runtime.h>
#include <math.h>

// Problem constants
#define EXPERTS 8
#define DEPTH 6
#define DIM 512
#define HEADS 8
#define DHEAD 64
#define MLP_DIM 512
#define PSZ 4
#define IMG 32
#define NCLS 10
#define BATCH 128
#define PD 48            // 3*4*4
#define NTOK 65          // 64 patches + cls

// ---------------------------------------------------------------------------
// Gate: logits[b,e] = x_flat[b,:] . gate_w[e,:] + gate_b[e]; top1 = argmax_e
// ---------------------------------------------------------------------------
__global__ __launch_bounds__(256) void gate_k(const float* __restrict__ x,
                                              const float* __restrict__ gw,
                                              const float* __restrict__ gb,
                                              int* __restrict__ top1) {
    int b = blockIdx.x, tid = threadIdx.x;
    const float* xb = x + (size_t)b * 3072;
    float acc[EXPERTS];
#pragma unroll
    for (int e = 0; e < EXPERTS; ++e) acc[e] = 0.f;
    for (int i = tid; i < 3072; i += 256) {
        float xv = xb[i];
#pragma unroll
        for (int e = 0; e < EXPERTS; ++e)
            acc[e] = fmaf(xv, gw[(size_t)e * 3072 + i], acc[e]);
    }
    __shared__ float red[256];
    __shared__ float logits[EXPERTS];
    for (int e = 0; e < EXPERTS; ++e) {
        red[tid] = acc[e];
        __syncthreads();
        for (int s = 128; s > 0; s >>= 1) {
            if (tid < s) red[tid] += red[tid + s];
            __syncthreads();
        }
        if (tid == 0) logits[e] = red[0] + gb[e];
        __syncthreads();
    }
    if (tid == 0) {
        int best = 0;
        float bv = logits[0];
        for (int e = 1; e < EXPERTS; ++e)
            if (logits[e] > bv) { bv = logits[e]; best = e; }
        top1[b] = best;
    }
}

// ---------------------------------------------------------------------------
// Patch embed: patchify -> LN1(48) -> matmul 48->512 + bias -> LN2(512)
//   -> +pos_emb. Also writes cls row (n==0): cls_tok + pos_emb[0].
// grid (65, B), block 256.
// ---------------------------------------------------------------------------
__global__ __launch_bounds__(256) void patch_k(const float* __restrict__ x,
                                               const float* __restrict__ pln1_g,
                                               const float* __restrict__ pln1_b,
                                               const float* __restrict__ patch_w,
                                               const float* __restrict__ patch_b,
                                               const float* __restrict__ pln2_g,
                                               const float* __restrict__ pln2_b,
                                               const float* __restrict__ cls_tok,
                                               const float* __restrict__ pos_emb,
                                               const int* __restrict__ top1,
                                               float* __restrict__ t) {
    int n = blockIdx.x;   // 0..64 (0 = cls)
    int b = blockIdx.y;
    int tid = threadIdx.x;
    int e = top1[b];
    float* trow = t + ((size_t)b * NTOK + n) * DIM;
    const float* pe = pos_emb + ((size_t)e * NTOK + n) * DIM;

    if (n == 0) {
        for (int d = tid; d < DIM; d += 256)
            trow[d] = cls_tok[e * DIM + d] + pe[d];
        return;
    }
    int pi = n - 1, h = pi >> 3, w = pi & 7;
    __shared__ float pv[PD];
    __shared__ float red[256];
    if (tid < PD) {
        int p1 = tid / 12, rem = tid % 12, p2 = rem / 3, c = rem % 3;
        pv[tid] = x[((size_t)b * 3 + c) * 1024 + (h * 4 + p1) * 32 + (w * 4 + p2)];
    }
    __syncthreads();
    float m = 0.f, q = 0.f;
    for (int j = 0; j < PD; ++j) { float v = pv[j]; m += v; q += v * v; }
    m *= (1.f / PD);
    q = q * (1.f / PD) - m * m;
    float rs = rsqrtf(q + 1e-5f);
    __syncthreads();
    if (tid < PD)
        pv[tid] = (pv[tid] - m) * rs * pln1_g[e * PD + tid] + pln1_b[e * PD + tid];
    __syncthreads();

    float acc0 = patch_b[e * DIM + tid];
    float acc1 = patch_b[e * DIM + tid + 256];
    for (int j = 0; j < PD; ++j) {
        float v = pv[j];
        const float* wr = patch_w + ((size_t)e * PD + j) * DIM;
        acc0 = fmaf(v, wr[tid], acc0);
        acc1 = fmaf(v, wr[tid + 256], acc1);
    }
    // LN over 512 outputs
    red[tid] = acc0 + acc1;
    __syncthreads();
    for (int s = 128; s > 0; s >>= 1) {
        if (tid < s) red[tid] += red[tid + s];
        __syncthreads();
    }
    float S = red[0];
    __syncthreads();
    red[tid] = acc0 * acc0 + acc1 * acc1;
    __syncthreads();
    for (int s = 128; s > 0; s >>= 1) {
        if (tid < s) red[tid] += red[tid + s];
        __syncthreads();
    }
    float Q = red[0];
    float mean = S * (1.f / DIM);
    float var = Q * (1.f / DIM) - mean * mean;
    float rs2 = rsqrtf(var + 1e-5f);
    trow[tid]       = (acc0 - mean) * rs2 * pln2_g[e * DIM + tid]       + pln2_b[e * DIM + tid]       + pe[tid];
    trow[tid + 256] = (acc1 - mean) * rs2 * pln2_g[e * DIM + tid + 256] + pln2_b[e * DIM + tid + 256] + pe[tid + 256];
}

// ---------------------------------------------------------------------------
// Row LayerNorm over DIM=512 with per-expert gamma/beta.
// grid (65, B), block 256, 2 elems/thread.
// ---------------------------------------------------------------------------
__global__ __launch_bounds__(256) void ln_k(const float* __restrict__ src,
                                            float* __restrict__ dst,
                                            const float* __restrict__ gbase,
                                            const float* __restrict__ bbase,
                                            const int* __restrict__ top1,
                                            int estride) {
    int n = blockIdx.x, b = blockIdx.y, tid = threadIdx.x;
    int e = top1[b];
    size_t row = ((size_t)b * NTOK + n) * DIM;
    const float* gamma = gbase + (size_t)e * estride;
    const float* beta  = bbase + (size_t)e * estride;
    float v0 = src[row + tid], v1 = src[row + tid + 256];
    __shared__ float red[256];
    red[tid] = v0 + v1;
    __syncthreads();
    for (int s = 128; s > 0; s >>= 1) {
        if (tid < s) red[tid] += red[tid + s];
        __syncthreads();
    }
    float S = red[0];
    __syncthreads();
    red[tid] = v0 * v0 + v1 * v1;
    __syncthreads();
    for (int s = 128; s > 0; s >>= 1) {
        if (tid < s) red[tid] += red[tid + s];
        __syncthreads();
    }
    float Q = red[0];
    float mean = S * (1.f / DIM);
    float var = Q * (1.f / DIM) - mean * mean;
    float rs = rsqrtf(var + 1e-5f);
    dst[row + tid]       = (v0 - mean) * rs * gamma[tid]       + beta[tid];
    dst[row + tid + 256] = (v1 - mean) * rs * gamma[tid + 256] + beta[tid + 256];
}

// ---------------------------------------------------------------------------
// FP32 tiled GEMM per batch item: C[65,N] = A[65,512] @ W[512,N] (+bias)(+res)
// grid (N/128, B), block 256. Thread: 2 cols x 17 rows.
// OP: 0 = store (qkv), 1 = bias + add into C (residual), 2 = bias + GELU store
// ---------------------------------------------------------------------------
template <int N, int OP>
__global__ __launch_bounds__(256) void gemm_k(const float* __restrict__ A,
                                              const float* __restrict__ Wbase,
                                              const float* __restrict__ Bbase,
                                              float* __restrict__ C,
                                              const int* __restrict__ top1,
                                              int westride, int bestride) {
    int ct = blockIdx.x, b = blockIdx.y, tid = threadIdx.x;
    int e = top1[b];
    const float* W = Wbase + (size_t)e * westride;
    const float* bias = nullptr;
    if (OP != 0) bias = Bbase + (size_t)e * bestride + ct * 128;
    int c0 = ct * 128;
    int lane = tid & 63, rg = tid >> 6;

    __shared__ __align__(16) float As[68 * 32];      // 65 rows used, pad rows garbage
    __shared__ __align__(16) float Ws[32 * 132];     // [kk][c], row pad 132 (16B-aligned)
    const float* Ab = A + (size_t)b * NTOK * 512;

    float acc0[17], acc1[17];
#pragma unroll
    for (int i = 0; i < 17; ++i) { acc0[i] = 0.f; acc1[i] = 0.f; }

    for (int k0 = 0; k0 < 512; k0 += 32) {
        for (int idx = tid; idx < 520; idx += 256) {   // 65 rows x 8 quads
            int r = idx >> 3, q2 = idx & 7;
            *(float4*)&As[r * 32 + q2 * 4] =
                *(const float4*)&Ab[(size_t)r * 512 + k0 + q2 * 4];
        }
        for (int idx = tid; idx < 1024; idx += 256) {  // 32 kk x 32 quads
            int kk = idx >> 5, cq = idx & 31;
            *(float4*)&Ws[kk * 132 + cq * 4] =
                *(const float4*)&W[(size_t)(k0 + kk) * N + c0 + cq * 4];
        }
        __syncthreads();
#pragma unroll
        for (int kq = 0; kq < 8; ++kq) {
            float w0[4], w1[4];
#pragma unroll
            for (int u = 0; u < 4; ++u) {
                w0[u] = Ws[(kq * 4 + u) * 132 + lane];
                w1[u] = Ws[(kq * 4 + u) * 132 + lane + 64];
            }
#pragma unroll
            for (int i = 0; i < 17; ++i) {
                float4 a = *(const float4*)&As[(rg + 4 * i) * 32 + kq * 4];
                acc0[i] = fmaf(a.x, w0[0], acc0[i]);
                acc0[i] = fmaf(a.y, w0[1], acc0[i]);
                acc0[i] = fmaf(a.z, w0[2], acc0[i]);
                acc0[i] = fmaf(a.w, w0[3], acc0[i]);
                acc1[i] = fmaf(a.x, w1[0], acc1[i]);
                acc1[i] = fmaf(a.y, w1[1], acc1[i]);
                acc1[i] = fmaf(a.z, w1[2], acc1[i]);
                acc1[i] = fmaf(a.w, w1[3], acc1[i]);
            }
        }
        __syncthreads();
    }
#pragma unroll
    for (int i = 0; i < 17; ++i) {
        int r = rg + 4 * i;
        if (r < NTOK) {
            size_t row = ((size_t)b * NTOK + r) * N;
            int cA = c0 + lane, cB = c0 + lane + 64;
            if (OP == 0) {
                C[row + cA] = acc0[i];
                C[row + cB] = acc1[i];
            } else if (OP == 1) {
                C[row + cA] += acc0[i] + bias[lane];
                C[row + cB] += acc1[i] + bias[lane + 64];
            } else {
                float v0 = acc0[i] + bias[lane];
                float v1 = acc1[i] + bias[lane + 64];
                C[row + cA] = v0 * 0.5f * (1.f + erff(v0 * 0.70710678118f));
                C[row + cB] = v1 * 0.5f * (1.f + erff(v1 * 0.70710678118f));
            }
        }
    }
}

// ---------------------------------------------------------------------------
// Attention for one (b,h): S=q@k^T*0.125, softmax rows (65), O=P@v.
// grid (H, B), block 256 (4 waves; wave w handles rows w, w+4, ...).
// qkv layout [B,65,1536] (q|k|v each 512 = 8 heads x 64). O -> o[B,65,512].
// ---------------------------------------------------------------------------
__global__ __launch_bounds__(256) void attn_k(const float* __restrict__ qkv,
                                              float* __restrict__ o) {
    int h = blockIdx.x, b = blockIdx.y, tid = threadIdx.x;
    __shared__ float Qs[NTOK * 64];
    __shared__ float Ks[NTOK * 65];   // padded row: 65
    __shared__ float Vs[NTOK * 64];
    for (int idx = tid; idx < NTOK * 64; idx += 256) {
        int n = idx >> 6, d = idx & 63;
        size_t base = ((size_t)b * NTOK + n) * 1536 + h * 64 + d;
        Qs[n * 64 + d] = qkv[base];
        Ks[n * 65 + d] = qkv[base + 512];
        Vs[n * 64 + d] = qkv[base + 1024];
    }
    __syncthreads();
    int wave = tid >> 6, lane = tid & 63;
    for (int i = wave; i < NTOK; i += 4) {
        const float* qrow = Qs + i * 64;
        const float* krow = Ks + lane * 65;
        float s = 0.f, s1 = 0.f;
        const float* klast = Ks + 64 * 65;
        for (int d = 0; d < 64; ++d) {
            float qv = qrow[d];
            s  = fmaf(qv, krow[d], s);
            s1 = fmaf(qv, klast[d], s1);   // col 64, same for all lanes
        }
        s *= 0.125f;
        s1 *= 0.125f;
        float mx = s;
        for (int off = 32; off > 0; off >>= 1) mx = fmaxf(mx, __shfl_xor(mx, off));
        mx = fmaxf(mx, s1);
        float p = expf(s - mx);
        float p1 = expf(s1 - mx);
        float tot = p;
        for (int off = 32; off > 0; off >>= 1) tot += __shfl_xor(tot, off);
        tot += p1;
        float inv = 1.f / tot;
        p *= inv;
        p1 *= inv;
        float oacc = p1 * Vs[64 * 64 + lane];
        for (int j = 0; j < 64; ++j) {
            float pj = __shfl(p, j);
            oacc = fmaf(pj, Vs[j * 64 + lane], oacc);
        }
        o[((size_t)b * NTOK + i) * DIM + h * 64 + lane] = oacc;
    }
}

// ---------------------------------------------------------------------------
// Final LN (row 0 only) + head: out[b,:] = LN(t[b,0,:]) @ head_w[e] + head_b[e]
// grid (B), block 64 (one wave).
// ---------------------------------------------------------------------------
__global__ __launch_bounds__(64) void final_k(const float* __restrict__ t,
                                              const float* __restrict__ fg,
                                              const float* __restrict__ fb,
                                              const float* __restrict__ hw,
                                              const float* __restrict__ hb,
                                              const int* __restrict__ top1,
                                              float* __restrict__ out) {
    int b = blockIdx.x, lane = threadIdx.x;
    int e = top1[b];
    const float* row = t + (size_t)b * NTOK * DIM;
    float v[8], s = 0.f, q = 0.f;
#pragma unroll
    for (int ii = 0; ii < 8; ++ii) {
        v[ii] = row[ii * 64 + lane];
        s += v[ii];
        q += v[ii] * v[ii];
    }
    for (int off = 32; off > 0; off >>= 1) {
        s += __shfl_xor(s, off);
        q += __shfl_xor(q, off);
    }
    float mean = s * (1.f / DIM);
    float var = q * (1.f / DIM) - mean * mean;
    float rs = rsqrtf(var + 1e-5f);
    float nv[8];
#pragma unroll
    for (int ii = 0; ii < 8; ++ii) {
        int d = ii * 64 + lane;
        nv[ii] = (v[ii] - mean) * rs * fg[e * DIM + d] + fb[e * DIM + d];
    }
    for (int c = 0; c < NCLS; ++c) {
        float p = 0.f;
#pragma unroll
        for (int ii = 0; ii < 8; ++ii) {
            int d = ii * 64 + lane;
            p = fmaf(nv[ii], hw[(size_t)e * DIM * NCLS + d * NCLS + c], p);
        }
        for (int off = 32; off > 0; off >>= 1) p += __shfl_xor(p, off);
        if (lane == 0) out[b * NCLS + c] = p + hb[e * NCLS + c];
    }
}

// ---------------------------------------------------------------------------
extern "C" void kernel_launch(void* const* d_in, const int* in_sizes, int n_in,
                              void* d_out, int out_size, void* d_ws, size_t ws_size,
                              hipStream_t stream) {
    const float* x       = (const float*)d_in[0];
    const float* gate_w  = (const float*)d_in[1];
    const float* gate_b  = (const float*)d_in[2];
    const float* pln1_g  = (const float*)d_in[3];
    const float* pln1_b  = (const float*)d_in[4];
    const float* patch_w = (const float*)d_in[5];
    const float* patch_b = (const float*)d_in[6];
    const float* pln2_g  = (const float*)d_in[7];
    const float* pln2_b  = (const float*)d_in[8];
    const float* cls_tok = (const float*)d_in[9];
    const float* pos_emb = (const float*)d_in[10];
    const float* aln_g   = (const float*)d_in[11];
    const float* aln_b   = (const float*)d_in[12];
    const float* qkv_w   = (const float*)d_in[13];
    const float* out_w   = (const float*)d_in[14];
    const float* out_b   = (const float*)d_in[15];
    const float* fln_g   = (const float*)d_in[16];
    const float* fln_b   = (const float*)d_in[17];
    const float* ff1_w   = (const float*)d_in[18];
    const float* ff1_b   = (const float*)d_in[19];
    const float* ff2_w   = (const float*)d_in[20];
    const float* ff2_b   = (const float*)d_in[21];
    const float* final_g = (const float*)d_in[22];
    const float* final_b = (const float*)d_in[23];
    const float* head_w  = (const float*)d_in[24];
    const float* head_b  = (const float*)d_in[25];
    float* out = (float*)d_out;

    // Workspace layout
    int* top1 = (int*)d_ws;
    float* t  = (float*)((char*)d_ws + 1024);                // [B,65,512]
    float* g  = t + (size_t)BATCH * NTOK * DIM;              // [B,65,512] (also attn out)
    float* qb = g + (size_t)BATCH * NTOK * DIM;              // [B,65,1536] (also ffn hidden)

    gate_k<<<BATCH, 256, 0, stream>>>(x, gate_w, gate_b, top1);
    patch_k<<<dim3(NTOK, BATCH), 256, 0, stream>>>(x, pln1_g, pln1_b, patch_w, patch_b,
                                                   pln2_g, pln2_b, cls_tok, pos_emb, top1, t);
    for (int l = 0; l < DEPTH; ++l) {
        ln_k<<<dim3(NTOK, BATCH), 256, 0, stream>>>(t, g, aln_g + l * DIM, aln_b + l * DIM,
                                                    top1, DEPTH * DIM);
        gemm_k<1536, 0><<<dim3(12, BATCH), 256, 0, stream>>>(
            g, qkv_w + (size_t)l * 512 * 1536, nullptr, qb, top1,
            DEPTH * 512 * 1536, 0);
        attn_k<<<dim3(HEADS, BATCH), 256, 0, stream>>>(qb, g);
        gemm_k<512, 1><<<dim3(4, BATCH), 256, 0, stream>>>(
            g, out_w + (size_t)l * 512 * 512, out_b + l * DIM, t, top1,
            DEPTH * 512 * 512, DEPTH * DIM);
        ln_k<<<dim3(NTOK, BATCH), 256, 0, stream>>>(t, g, fln_g + l * DIM, fln_b + l * DIM,
                                                    top1, DEPTH * DIM);
        gemm_k<512, 2><<<dim3(4, BATCH), 256, 0, stream>>>(
            g, ff1_w + (size_t)l * 512 * 512, ff1_b + l * DIM, qb, top1,
            DEPTH * 512 * 512, DEPTH * DIM);
        gemm_k<512, 1><<<dim3(4, BATCH), 256, 0, stream>>>(
            qb, ff2_w + (size_t)l * 512 * 512, ff2_b + l * DIM, t, top1,
            DEPTH * 512 * 512, DEPTH * DIM);
    }
    final_k<<<BATCH, 64, 0, stream>>>(t, final_g, final_b, head_w, head_b, top1, out);
}

// Round 2
// 1909.940 us; speedup vs baseline: 2.4563x; 2.4563x over previous
//
#include <hip/hip_runtime.h>
#include <math.h>

#define EXPERTS 8
#define DEPTH 6
#define DIM 512
#define HEADS 8
#define NCLS 10
#define BATCH 128
#define PD 48
#define NTOK 65

typedef __attribute__((ext_vector_type(4))) float f32x4;
typedef __attribute__((ext_vector_type(8))) __bf16 bf16x8;
typedef unsigned short u16;

__device__ inline u16 f2bf(float f) {
    union { float f; unsigned u; } v; v.f = f;
    unsigned r = v.u + 0x7FFFu + ((v.u >> 16) & 1u);
    return (u16)(r >> 16);
}
__device__ inline float bf2f(u16 s) {
    union { unsigned u; float f; } v; v.u = ((unsigned)s) << 16;
    return v.f;
}

// ---------------------------------------------------------------------------
// Gate (exact fp32 — routing must not flip)
// ---------------------------------------------------------------------------
__global__ __launch_bounds__(256) void gate_k(const float* __restrict__ x,
                                              const float* __restrict__ gw,
                                              const float* __restrict__ gb,
                                              int* __restrict__ top1) {
    int b = blockIdx.x, tid = threadIdx.x;
    const float* xb = x + (size_t)b * 3072;
    float acc[EXPERTS];
#pragma unroll
    for (int e = 0; e < EXPERTS; ++e) acc[e] = 0.f;
    for (int i = tid; i < 3072; i += 256) {
        float xv = xb[i];
#pragma unroll
        for (int e = 0; e < EXPERTS; ++e)
            acc[e] = fmaf(xv, gw[(size_t)e * 3072 + i], acc[e]);
    }
    __shared__ float red[256];
    __shared__ float logits[EXPERTS];
    for (int e = 0; e < EXPERTS; ++e) {
        red[tid] = acc[e];
        __syncthreads();
        for (int s = 128; s > 0; s >>= 1) {
            if (tid < s) red[tid] += red[tid + s];
            __syncthreads();
        }
        if (tid == 0) logits[e] = red[0] + gb[e];
        __syncthreads();
    }
    if (tid == 0) {
        int best = 0;
        float bv = logits[0];
        for (int e = 1; e < EXPERTS; ++e)
            if (logits[e] > bv) { bv = logits[e]; best = e; }
        top1[b] = best;
    }
}

// ---------------------------------------------------------------------------
// Patch embed (fp32, writes residual stream t)
// ---------------------------------------------------------------------------
__global__ __launch_bounds__(256) void patch_k(const float* __restrict__ x,
                                               const float* __restrict__ pln1_g,
                                               const float* __restrict__ pln1_b,
                                               const float* __restrict__ patch_w,
                                               const float* __restrict__ patch_b,
                                               const float* __restrict__ pln2_g,
                                               const float* __restrict__ pln2_b,
                                               const float* __restrict__ cls_tok,
                                               const float* __restrict__ pos_emb,
                                               const int* __restrict__ top1,
                                               float* __restrict__ t) {
    int n = blockIdx.x, b = blockIdx.y, tid = threadIdx.x;
    int e = top1[b];
    float* trow = t + ((size_t)b * NTOK + n) * DIM;
    const float* pe = pos_emb + ((size_t)e * NTOK + n) * DIM;

    if (n == 0) {
        for (int d = tid; d < DIM; d += 256)
            trow[d] = cls_tok[e * DIM + d] + pe[d];
        return;
    }
    int pi = n - 1, h = pi >> 3, w = pi & 7;
    __shared__ float pv[PD];
    __shared__ float red[256];
    if (tid < PD) {
        int p1 = tid / 12, rem = tid % 12, p2 = rem / 3, c = rem % 3;
        pv[tid] = x[((size_t)b * 3 + c) * 1024 + (h * 4 + p1) * 32 + (w * 4 + p2)];
    }
    __syncthreads();
    float m = 0.f, q = 0.f;
    for (int j = 0; j < PD; ++j) { float v = pv[j]; m += v; q += v * v; }
    m *= (1.f / PD);
    q = q * (1.f / PD) - m * m;
    float rs = rsqrtf(q + 1e-5f);
    __syncthreads();
    if (tid < PD)
        pv[tid] = (pv[tid] - m) * rs * pln1_g[e * PD + tid] + pln1_b[e * PD + tid];
    __syncthreads();

    float acc0 = patch_b[e * DIM + tid];
    float acc1 = patch_b[e * DIM + tid + 256];
    for (int j = 0; j < PD; ++j) {
        float v = pv[j];
        const float* wr = patch_w + ((size_t)e * PD + j) * DIM;
        acc0 = fmaf(v, wr[tid], acc0);
        acc1 = fmaf(v, wr[tid + 256], acc1);
    }
    red[tid] = acc0 + acc1;
    __syncthreads();
    for (int s = 128; s > 0; s >>= 1) {
        if (tid < s) red[tid] += red[tid + s];
        __syncthreads();
    }
    float S = red[0];
    __syncthreads();
    red[tid] = acc0 * acc0 + acc1 * acc1;
    __syncthreads();
    for (int s = 128; s > 0; s >>= 1) {
        if (tid < s) red[tid] += red[tid + s];
        __syncthreads();
    }
    float Q = red[0];
    float mean = S * (1.f / DIM);
    float var = Q * (1.f / DIM) - mean * mean;
    float rs2 = rsqrtf(var + 1e-5f);
    trow[tid]       = (acc0 - mean) * rs2 * pln2_g[e * DIM + tid]       + pln2_b[e * DIM + tid]       + pe[tid];
    trow[tid + 256] = (acc1 - mean) * rs2 * pln2_g[e * DIM + tid + 256] + pln2_b[e * DIM + tid + 256] + pe[tid + 256];
}

// ---------------------------------------------------------------------------
// LayerNorm: fp32 src -> bf16 dst
// ---------------------------------------------------------------------------
__global__ __launch_bounds__(256) void ln_k(const float* __restrict__ src,
                                            u16* __restrict__ dst,
                                            const float* __restrict__ gbase,
                                            const float* __restrict__ bbase,
                                            const int* __restrict__ top1,
                                            int estride) {
    int n = blockIdx.x, b = blockIdx.y, tid = threadIdx.x;
    int e = top1[b];
    size_t row = ((size_t)b * NTOK + n) * DIM;
    const float* gamma = gbase + (size_t)e * estride;
    const float* beta  = bbase + (size_t)e * estride;
    float v0 = src[row + tid], v1 = src[row + tid + 256];
    __shared__ float red[256];
    red[tid] = v0 + v1;
    __syncthreads();
    for (int s = 128; s > 0; s >>= 1) {
        if (tid < s) red[tid] += red[tid + s];
        __syncthreads();
    }
    float S = red[0];
    __syncthreads();
    red[tid] = v0 * v0 + v1 * v1;
    __syncthreads();
    for (int s = 128; s > 0; s >>= 1) {
        if (tid < s) red[tid] += red[tid + s];
        __syncthreads();
    }
    float Q = red[0];
    float mean = S * (1.f / DIM);
    float var = Q * (1.f / DIM) - mean * mean;
    float rs = rsqrtf(var + 1e-5f);
    dst[row + tid]       = f2bf((v0 - mean) * rs * gamma[tid]       + beta[tid]);
    dst[row + tid + 256] = f2bf((v1 - mean) * rs * gamma[tid + 256] + beta[tid + 256]);
}

// ---------------------------------------------------------------------------
// MFMA bf16 GEMM: C[65,N] = A[65,512](bf16) @ W[512,N](fp32->bf16) per item.
// grid (N/128, B), block 256 (4 waves). Wave w: cols [c0+w*32, +32), M=80.
// OP: 0 = store bf16 (qkv, no bias); 1 = fp32 residual += acc+bias;
//     2 = bias + exact GELU -> bf16
// ---------------------------------------------------------------------------
template <int N, int OP>
__global__ __launch_bounds__(256) void mgemm_k(const u16* __restrict__ A,
                                               const float* __restrict__ Wbase,
                                               const float* __restrict__ Bbase,
                                               void* __restrict__ Cptr,
                                               const int* __restrict__ top1,
                                               int westride, int bestride) {
    int ct = blockIdx.x, b = blockIdx.y, tid = threadIdx.x;
    int e = top1[b];
    const float* W = Wbase + (size_t)e * westride + ct * 128;
    int c0 = ct * 128;
    int lane = tid & 63, w = tid >> 6;

    // [kgroup][row][8] subtiles: every frag read is one aligned ds_read_b128,
    // 2-way bank aliasing (free).
    __shared__ __align__(16) u16 As[4][80][8];
    __shared__ __align__(16) u16 Bs[4][128][8];

    const u16* Ab = A + (size_t)b * NTOK * 512;

    f32x4 acc[5][2];
#pragma unroll
    for (int mt = 0; mt < 5; ++mt)
#pragma unroll
        for (int j = 0; j < 2; ++j) acc[mt][j] = (f32x4){0.f, 0.f, 0.f, 0.f};

    int rl = lane & 15, kg = lane >> 4;

    for (int k0 = 0; k0 < 512; k0 += 32) {
        // Stage A: 320 x 16B chunks (rows >=65 zeroed)
        for (int idx = tid; idx < 320; idx += 256) {
            int r = idx >> 2, q = idx & 3;
            int4 v = {0, 0, 0, 0};
            if (r < NTOK) v = *(const int4*)&Ab[(size_t)r * 512 + k0 + q * 8];
            *(int4*)&As[q][r][0] = v;
        }
        // Stage B transposed+converted: thread task = (col c, kgroup kq):
        // 8 lane-coalesced strided loads -> one int4 LDS write.
        for (int idx = tid; idx < 512; idx += 256) {
            int c = idx & 127, kq = idx >> 7;
            u16 tmp[8];
#pragma unroll
            for (int j = 0; j < 8; ++j)
                tmp[j] = f2bf(W[(size_t)(k0 + kq * 8 + j) * N + c]);
            *(int4*)&Bs[kq][c][0] = *(int4*)tmp;
        }
        __syncthreads();
        bf16x8 bfr0 = *(const bf16x8*)&Bs[kg][(w * 2) * 16 + rl][0];
        bf16x8 bfr1 = *(const bf16x8*)&Bs[kg][(w * 2 + 1) * 16 + rl][0];
#pragma unroll
        for (int mt = 0; mt < 5; ++mt) {
            bf16x8 av = *(const bf16x8*)&As[kg][mt * 16 + rl][0];
            acc[mt][0] = __builtin_amdgcn_mfma_f32_16x16x32_bf16(av, bfr0, acc[mt][0], 0, 0, 0);
            acc[mt][1] = __builtin_amdgcn_mfma_f32_16x16x32_bf16(av, bfr1, acc[mt][1], 0, 0, 0);
        }
        __syncthreads();
    }

    // Epilogue: D elem r -> row (lane>>4)*4+r, col lane&15 (m89 layout)
    int rh = lane >> 4;
#pragma unroll
    for (int mt = 0; mt < 5; ++mt)
#pragma unroll
        for (int j = 0; j < 2; ++j)
#pragma unroll
            for (int r = 0; r < 4; ++r) {
                int m = mt * 16 + rh * 4 + r;
                if (m >= NTOK) continue;
                int c = c0 + (w * 2 + j) * 16 + rl;
                float v = acc[mt][j][r];
                size_t o = ((size_t)b * NTOK + m) * N + c;
                if (OP == 0) {
                    ((u16*)Cptr)[o] = f2bf(v);
                } else if (OP == 1) {
                    float* C = (float*)Cptr;
                    C[o] += v + Bbase[(size_t)e * bestride + c];
                } else {
                    float vb = v + Bbase[(size_t)e * bestride + c];
                    float gl = vb * 0.5f * (1.f + erff(vb * 0.70710678118f));
                    ((u16*)Cptr)[o] = f2bf(gl);
                }
            }
}

// ---------------------------------------------------------------------------
// Attention: bf16 qkv in, fp32 math, bf16 out. grid (H, B), block 256.
// ---------------------------------------------------------------------------
__global__ __launch_bounds__(256) void attn_k(const u16* __restrict__ qkv,
                                              u16* __restrict__ o) {
    int h = blockIdx.x, b = blockIdx.y, tid = threadIdx.x;
    __shared__ float Qs[NTOK * 64];
    __shared__ float Ks[NTOK * 65];
    __shared__ float Vs[NTOK * 64];
    for (int idx = tid; idx < NTOK * 16; idx += 256) {
        int n = idx >> 4, dq = (idx & 15) * 4;
        size_t base = ((size_t)b * NTOK + n) * 1536 + h * 64 + dq;
        ushort4 q4 = *(const ushort4*)&qkv[base];
        ushort4 k4 = *(const ushort4*)&qkv[base + 512];
        ushort4 v4 = *(const ushort4*)&qkv[base + 1024];
        Qs[n * 64 + dq] = bf2f(q4.x); Qs[n * 64 + dq + 1] = bf2f(q4.y);
        Qs[n * 64 + dq + 2] = bf2f(q4.z); Qs[n * 64 + dq + 3] = bf2f(q4.w);
        Ks[n * 65 + dq] = bf2f(k4.x); Ks[n * 65 + dq + 1] = bf2f(k4.y);
        Ks[n * 65 + dq + 2] = bf2f(k4.z); Ks[n * 65 + dq + 3] = bf2f(k4.w);
        Vs[n * 64 + dq] = bf2f(v4.x); Vs[n * 64 + dq + 1] = bf2f(v4.y);
        Vs[n * 64 + dq + 2] = bf2f(v4.z); Vs[n * 64 + dq + 3] = bf2f(v4.w);
    }
    __syncthreads();
    int wave = tid >> 6, lane = tid & 63;
    for (int i = wave; i < NTOK; i += 4) {
        const float* qrow = Qs + i * 64;
        const float* krow = Ks + lane * 65;
        const float* klast = Ks + 64 * 65;
        float s = 0.f, s1 = 0.f;
        for (int d = 0; d < 64; ++d) {
            float qv = qrow[d];
            s  = fmaf(qv, krow[d], s);
            s1 = fmaf(qv, klast[d], s1);
        }
        s *= 0.125f;
        s1 *= 0.125f;
        float mx = s;
        for (int off = 32; off > 0; off >>= 1) mx = fmaxf(mx, __shfl_xor(mx, off));
        mx = fmaxf(mx, s1);
        float p = expf(s - mx);
        float p1 = expf(s1 - mx);
        float tot = p;
        for (int off = 32; off > 0; off >>= 1) tot += __shfl_xor(tot, off);
        tot += p1;
        float inv = 1.f / tot;
        p *= inv;
        p1 *= inv;
        float oacc = p1 * Vs[64 * 64 + lane];
        for (int j = 0; j < 64; ++j) {
            float pj = __shfl(p, j);
            oacc = fmaf(pj, Vs[j * 64 + lane], oacc);
        }
        o[((size_t)b * NTOK + i) * DIM + h * 64 + lane] = f2bf(oacc);
    }
}

// ---------------------------------------------------------------------------
// Final LN (row 0) + head (fp32)
// ---------------------------------------------------------------------------
__global__ __launch_bounds__(64) void final_k(const float* __restrict__ t,
                                              const float* __restrict__ fg,
                                              const float* __restrict__ fb,
                                              const float* __restrict__ hw,
                                              const float* __restrict__ hb,
                                              const int* __restrict__ top1,
                                              float* __restrict__ out) {
    int b = blockIdx.x, lane = threadIdx.x;
    int e = top1[b];
    const float* row = t + (size_t)b * NTOK * DIM;
    float v[8], s = 0.f, q = 0.f;
#pragma unroll
    for (int ii = 0; ii < 8; ++ii) {
        v[ii] = row[ii * 64 + lane];
        s += v[ii];
        q += v[ii] * v[ii];
    }
    for (int off = 32; off > 0; off >>= 1) {
        s += __shfl_xor(s, off);
        q += __shfl_xor(q, off);
    }
    float mean = s * (1.f / DIM);
    float var = q * (1.f / DIM) - mean * mean;
    float rs = rsqrtf(var + 1e-5f);
    float nv[8];
#pragma unroll
    for (int ii = 0; ii < 8; ++ii) {
        int d = ii * 64 + lane;
        nv[ii] = (v[ii] - mean) * rs * fg[e * DIM + d] + fb[e * DIM + d];
    }
    for (int c = 0; c < NCLS; ++c) {
        float p = 0.f;
#pragma unroll
        for (int ii = 0; ii < 8; ++ii) {
            int d = ii * 64 + lane;
            p = fmaf(nv[ii], hw[(size_t)e * DIM * NCLS + d * NCLS + c], p);
        }
        for (int off = 32; off > 0; off >>= 1) p += __shfl_xor(p, off);
        if (lane == 0) out[b * NCLS + c] = p + hb[e * NCLS + c];
    }
}

// ---------------------------------------------------------------------------
extern "C" void kernel_launch(void* const* d_in, const int* in_sizes, int n_in,
                              void* d_out, int out_size, void* d_ws, size_t ws_size,
                              hipStream_t stream) {
    const float* x       = (const float*)d_in[0];
    const float* gate_w  = (const float*)d_in[1];
    const float* gate_b  = (const float*)d_in[2];
    const float* pln1_g  = (const float*)d_in[3];
    const float* pln1_b  = (const float*)d_in[4];
    const float* patch_w = (const float*)d_in[5];
    const float* patch_b = (const float*)d_in[6];
    const float* pln2_g  = (const float*)d_in[7];
    const float* pln2_b  = (const float*)d_in[8];
    const float* cls_tok = (const float*)d_in[9];
    const float* pos_emb = (const float*)d_in[10];
    const float* aln_g   = (const float*)d_in[11];
    const float* aln_b   = (const float*)d_in[12];
    const float* qkv_w   = (const float*)d_in[13];
    const float* out_w   = (const float*)d_in[14];
    const float* out_b   = (const float*)d_in[15];
    const float* fln_g   = (const float*)d_in[16];
    const float* fln_b   = (const float*)d_in[17];
    const float* ff1_w   = (const float*)d_in[18];
    const float* ff1_b   = (const float*)d_in[19];
    const float* ff2_w   = (const float*)d_in[20];
    const float* ff2_b   = (const float*)d_in[21];
    const float* final_g = (const float*)d_in[22];
    const float* final_b = (const float*)d_in[23];
    const float* head_w  = (const float*)d_in[24];
    const float* head_b  = (const float*)d_in[25];
    float* out = (float*)d_out;

    // Workspace layout
    int* top1 = (int*)d_ws;
    float* t  = (float*)((char*)d_ws + 1024);                // fp32 [B,65,512]
    u16* g16  = (u16*)(t + (size_t)BATCH * NTOK * DIM);      // bf16 [B,65,512]
    u16* qb16 = g16 + (size_t)BATCH * NTOK * DIM;            // bf16 [B,65,1536]

    gate_k<<<BATCH, 256, 0, stream>>>(x, gate_w, gate_b, top1);
    patch_k<<<dim3(NTOK, BATCH), 256, 0, stream>>>(x, pln1_g, pln1_b, patch_w, patch_b,
                                                   pln2_g, pln2_b, cls_tok, pos_emb, top1, t);
    for (int l = 0; l < DEPTH; ++l) {
        ln_k<<<dim3(NTOK, BATCH), 256, 0, stream>>>(t, g16, aln_g + l * DIM, aln_b + l * DIM,
                                                    top1, DEPTH * DIM);
        mgemm_k<1536, 0><<<dim3(12, BATCH), 256, 0, stream>>>(
            g16, qkv_w + (size_t)l * 512 * 1536, nullptr, qb16, top1,
            DEPTH * 512 * 1536, 0);
        attn_k<<<dim3(HEADS, BATCH), 256, 0, stream>>>(qb16, g16);
        mgemm_k<512, 1><<<dim3(4, BATCH), 256, 0, stream>>>(
            g16, out_w + (size_t)l * 512 * 512, out_b + l * DIM, t, top1,
            DEPTH * 512 * 512, DEPTH * DIM);
        ln_k<<<dim3(NTOK, BATCH), 256, 0, stream>>>(t, g16, fln_g + l * DIM, fln_b + l * DIM,
                                                    top1, DEPTH * DIM);
        mgemm_k<512, 2><<<dim3(4, BATCH), 256, 0, stream>>>(
            g16, ff1_w + (size_t)l * 512 * 512, ff1_b + l * DIM, qb16, top1,
            DEPTH * 512 * 512, DEPTH * DIM);
        mgemm_k<512, 1><<<dim3(4, BATCH), 256, 0, stream>>>(
            qb16, ff2_w + (size_t)l * 512 * 512, ff2_b + l * DIM, t, top1,
            DEPTH * 512 * 512, DEPTH * DIM);
    }
    final_k<<<BATCH, 64, 0, stream>>>(t, final_g, final_b, head_w, head_b, top1, out);
}

// Round 3
// 1248.090 us; speedup vs baseline: 3.7588x; 1.5303x over previous
//
#include <hip/hip_runtime.h>
#include <math.h>

#define EXPERTS 8
#define DEPTH 6
#define DIM 512
#define HEADS 8
#define NCLS 10
#define BATCH 128
#define PD 48
#define NTOK 65

typedef __attribute__((ext_vector_type(4))) float f32x4;
typedef __attribute__((ext_vector_type(8))) __bf16 bf16x8;
typedef unsigned short u16;

__device__ inline u16 f2bf(float f) {
    union { float f; unsigned u; } v; v.f = f;
    unsigned r = v.u + 0x7FFFu + ((v.u >> 16) & 1u);
    return (u16)(r >> 16);
}
__device__ inline float bf2f(u16 s) {
    union { unsigned u; float f; } v; v.u = ((unsigned)s) << 16;
    return v.f;
}

// ---------------------------------------------------------------------------
// Gate (exact fp32 — routing must not flip)
// ---------------------------------------------------------------------------
__global__ __launch_bounds__(256) void gate_k(const float* __restrict__ x,
                                              const float* __restrict__ gw,
                                              const float* __restrict__ gb,
                                              int* __restrict__ top1) {
    int b = blockIdx.x, tid = threadIdx.x;
    const float* xb = x + (size_t)b * 3072;
    float acc[EXPERTS];
#pragma unroll
    for (int e = 0; e < EXPERTS; ++e) acc[e] = 0.f;
    for (int i = tid; i < 3072; i += 256) {
        float xv = xb[i];
#pragma unroll
        for (int e = 0; e < EXPERTS; ++e)
            acc[e] = fmaf(xv, gw[(size_t)e * 3072 + i], acc[e]);
    }
    __shared__ float red[256];
    __shared__ float logits[EXPERTS];
    for (int e = 0; e < EXPERTS; ++e) {
        red[tid] = acc[e];
        __syncthreads();
        for (int s = 128; s > 0; s >>= 1) {
            if (tid < s) red[tid] += red[tid + s];
            __syncthreads();
        }
        if (tid == 0) logits[e] = red[0] + gb[e];
        __syncthreads();
    }
    if (tid == 0) {
        int best = 0;
        float bv = logits[0];
        for (int e = 1; e < EXPERTS; ++e)
            if (logits[e] > bv) { bv = logits[e]; best = e; }
        top1[b] = best;
    }
}

// ---------------------------------------------------------------------------
// Patch embed (fp32, writes residual stream t)
// ---------------------------------------------------------------------------
__global__ __launch_bounds__(256) void patch_k(const float* __restrict__ x,
                                               const float* __restrict__ pln1_g,
                                               const float* __restrict__ pln1_b,
                                               const float* __restrict__ patch_w,
                                               const float* __restrict__ patch_b,
                                               const float* __restrict__ pln2_g,
                                               const float* __restrict__ pln2_b,
                                               const float* __restrict__ cls_tok,
                                               const float* __restrict__ pos_emb,
                                               const int* __restrict__ top1,
                                               float* __restrict__ t) {
    int n = blockIdx.x, b = blockIdx.y, tid = threadIdx.x;
    int e = top1[b];
    float* trow = t + ((size_t)b * NTOK + n) * DIM;
    const float* pe = pos_emb + ((size_t)e * NTOK + n) * DIM;

    if (n == 0) {
        for (int d = tid; d < DIM; d += 256)
            trow[d] = cls_tok[e * DIM + d] + pe[d];
        return;
    }
    int pi = n - 1, h = pi >> 3, w = pi & 7;
    __shared__ float pv[PD];
    __shared__ float red[256];
    if (tid < PD) {
        int p1 = tid / 12, rem = tid % 12, p2 = rem / 3, c = rem % 3;
        pv[tid] = x[((size_t)b * 3 + c) * 1024 + (h * 4 + p1) * 32 + (w * 4 + p2)];
    }
    __syncthreads();
    float m = 0.f, q = 0.f;
    for (int j = 0; j < PD; ++j) { float v = pv[j]; m += v; q += v * v; }
    m *= (1.f / PD);
    q = q * (1.f / PD) - m * m;
    float rs = rsqrtf(q + 1e-5f);
    __syncthreads();
    if (tid < PD)
        pv[tid] = (pv[tid] - m) * rs * pln1_g[e * PD + tid] + pln1_b[e * PD + tid];
    __syncthreads();

    float acc0 = patch_b[e * DIM + tid];
    float acc1 = patch_b[e * DIM + tid + 256];
    for (int j = 0; j < PD; ++j) {
        float v = pv[j];
        const float* wr = patch_w + ((size_t)e * PD + j) * DIM;
        acc0 = fmaf(v, wr[tid], acc0);
        acc1 = fmaf(v, wr[tid + 256], acc1);
    }
    red[tid] = acc0 + acc1;
    __syncthreads();
    for (int s = 128; s > 0; s >>= 1) {
        if (tid < s) red[tid] += red[tid + s];
        __syncthreads();
    }
    float S = red[0];
    __syncthreads();
    red[tid] = acc0 * acc0 + acc1 * acc1;
    __syncthreads();
    for (int s = 128; s > 0; s >>= 1) {
        if (tid < s) red[tid] += red[tid + s];
        __syncthreads();
    }
    float Q = red[0];
    float mean = S * (1.f / DIM);
    float var = Q * (1.f / DIM) - mean * mean;
    float rs2 = rsqrtf(var + 1e-5f);
    trow[tid]       = (acc0 - mean) * rs2 * pln2_g[e * DIM + tid]       + pln2_b[e * DIM + tid]       + pe[tid];
    trow[tid + 256] = (acc1 - mean) * rs2 * pln2_g[e * DIM + tid + 256] + pln2_b[e * DIM + tid + 256] + pe[tid + 256];
}

// ---------------------------------------------------------------------------
// LayerNorm: fp32 src -> bf16 dst
// ---------------------------------------------------------------------------
__global__ __launch_bounds__(256) void ln_k(const float* __restrict__ src,
                                            u16* __restrict__ dst,
                                            const float* __restrict__ gbase,
                                            const float* __restrict__ bbase,
                                            const int* __restrict__ top1,
                                            int estride) {
    int n = blockIdx.x, b = blockIdx.y, tid = threadIdx.x;
    int e = top1[b];
    size_t row = ((size_t)b * NTOK + n) * DIM;
    const float* gamma = gbase + (size_t)e * estride;
    const float* beta  = bbase + (size_t)e * estride;
    float v0 = src[row + tid], v1 = src[row + tid + 256];
    __shared__ float red[256];
    red[tid] = v0 + v1;
    __syncthreads();
    for (int s = 128; s > 0; s >>= 1) {
        if (tid < s) red[tid] += red[tid + s];
        __syncthreads();
    }
    float S = red[0];
    __syncthreads();
    red[tid] = v0 * v0 + v1 * v1;
    __syncthreads();
    for (int s = 128; s > 0; s >>= 1) {
        if (tid < s) red[tid] += red[tid + s];
        __syncthreads();
    }
    float Q = red[0];
    float mean = S * (1.f / DIM);
    float var = Q * (1.f / DIM) - mean * mean;
    float rs = rsqrtf(var + 1e-5f);
    dst[row + tid]       = f2bf((v0 - mean) * rs * gamma[tid]       + beta[tid]);
    dst[row + tid + 256] = f2bf((v1 - mean) * rs * gamma[tid + 256] + beta[tid + 256]);
}

// ---------------------------------------------------------------------------
// Weight convert: fp32 [cnt][512][N] -> bf16 [cnt][N][512] (transpose).
// grid (N/32, 512/32, cnt), block 256.
// ---------------------------------------------------------------------------
__global__ __launch_bounds__(256) void wconv_k(const float* __restrict__ src,
                                               u16* __restrict__ dst, int N) {
    __shared__ float tile[32][33];
    int n0 = blockIdx.x * 32, k0 = blockIdx.y * 32, m = blockIdx.z;
    const float* s = src + (size_t)m * 512 * N;
    u16* d = dst + (size_t)m * 512 * N;
    int r = threadIdx.x >> 5, c = threadIdx.x & 31;
#pragma unroll
    for (int i = 0; i < 4; ++i)
        tile[r + i * 8][c] = s[(size_t)(k0 + r + i * 8) * N + n0 + c];
    __syncthreads();
#pragma unroll
    for (int i = 0; i < 4; ++i)
        d[(size_t)(n0 + r + i * 8) * 512 + k0 + c] = f2bf(tile[c][r + i * 8]);
}

// ---------------------------------------------------------------------------
// MFMA GEMM (preconverted bf16 Wt[n][k]): C[65,N] = A[65,512] @ W.
// grid (N/128, B), block 256 (4 waves), K-step 64, M=80 (5 m-tiles).
// OP: 0 = store bf16; 1 = fp32 residual += acc+bias; 2 = bias+GELU -> bf16
// ---------------------------------------------------------------------------
template <int N, int OP>
__global__ __launch_bounds__(256) void mgemm2_k(const u16* __restrict__ A,
                                                const u16* __restrict__ Wtbase,
                                                const float* __restrict__ Bbase,
                                                void* __restrict__ Cptr,
                                                const int* __restrict__ top1,
                                                int westride, int bestride) {
    int ct = blockIdx.x, b = blockIdx.y, tid = threadIdx.x;
    int e = top1[b];
    const u16* Wt = Wtbase + (size_t)e * westride;
    int c0 = ct * 128;
    int lane = tid & 63, w = tid >> 6;
    int rl = lane & 15, kg = lane >> 4;

    __shared__ __align__(16) u16 As[80 * 72];   // rows padded to 72 elems
    __shared__ __align__(16) u16 Bs[128 * 72];

    const u16* Ab = A + (size_t)b * NTOK * 512;

    // zero pad rows 65..79 once (never rewritten)
    for (int idx = tid; idx < 135; idx += 256) {
        int r = 65 + idx / 9, q = idx % 9;
        *(int4*)&As[r * 72 + q * 8] = (int4){0, 0, 0, 0};
    }

    f32x4 acc[5][2];
#pragma unroll
    for (int mt = 0; mt < 5; ++mt)
#pragma unroll
        for (int j = 0; j < 2; ++j) acc[mt][j] = (f32x4){0.f, 0.f, 0.f, 0.f};

    for (int k0 = 0; k0 < 512; k0 += 64) {
        for (int idx = tid; idx < 520; idx += 256) {
            int r = idx >> 3, q = idx & 7;
            *(int4*)&As[r * 72 + q * 8] = *(const int4*)&Ab[(size_t)r * 512 + k0 + q * 8];
        }
        for (int idx = tid; idx < 1024; idx += 256) {
            int c = idx >> 3, q = idx & 7;
            *(int4*)&Bs[c * 72 + q * 8] = *(const int4*)&Wt[(size_t)(c0 + c) * 512 + k0 + q * 8];
        }
        __syncthreads();
#pragma unroll
        for (int ks = 0; ks < 2; ++ks) {
            bf16x8 bv0 = *(const bf16x8*)&Bs[((w * 2) * 16 + rl) * 72 + ks * 32 + kg * 8];
            bf16x8 bv1 = *(const bf16x8*)&Bs[((w * 2 + 1) * 16 + rl) * 72 + ks * 32 + kg * 8];
#pragma unroll
            for (int mt = 0; mt < 5; ++mt) {
                bf16x8 av = *(const bf16x8*)&As[(mt * 16 + rl) * 72 + ks * 32 + kg * 8];
                acc[mt][0] = __builtin_amdgcn_mfma_f32_16x16x32_bf16(av, bv0, acc[mt][0], 0, 0, 0);
                acc[mt][1] = __builtin_amdgcn_mfma_f32_16x16x32_bf16(av, bv1, acc[mt][1], 0, 0, 0);
            }
        }
        __syncthreads();
    }

    int rh = lane >> 4;
#pragma unroll
    for (int mt = 0; mt < 5; ++mt)
#pragma unroll
        for (int j = 0; j < 2; ++j)
#pragma unroll
            for (int r = 0; r < 4; ++r) {
                int m = mt * 16 + rh * 4 + r;
                if (m >= NTOK) continue;
                int c = c0 + (w * 2 + j) * 16 + rl;
                float v = acc[mt][j][r];
                size_t o = ((size_t)b * NTOK + m) * N + c;
                if (OP == 0) {
                    ((u16*)Cptr)[o] = f2bf(v);
                } else if (OP == 1) {
                    float* C = (float*)Cptr;
                    C[o] += v + Bbase[(size_t)e * bestride + c];
                } else {
                    float vb = v + Bbase[(size_t)e * bestride + c];
                    float gl = vb * 0.5f * (1.f + erff(vb * 0.70710678118f));
                    ((u16*)Cptr)[o] = f2bf(gl);
                }
            }
}

// ---------------------------------------------------------------------------
// Fallback MFMA GEMM (fp32 weights, converted during staging) — round-2 path.
// ---------------------------------------------------------------------------
template <int N, int OP>
__global__ __launch_bounds__(256) void mgemm_k(const u16* __restrict__ A,
                                               const float* __restrict__ Wbase,
                                               const float* __restrict__ Bbase,
                                               void* __restrict__ Cptr,
                                               const int* __restrict__ top1,
                                               int westride, int bestride) {
    int ct = blockIdx.x, b = blockIdx.y, tid = threadIdx.x;
    int e = top1[b];
    const float* W = Wbase + (size_t)e * westride + ct * 128;
    int c0 = ct * 128;
    int lane = tid & 63, w = tid >> 6;

    __shared__ __align__(16) u16 As[4][80][8];
    __shared__ __align__(16) u16 Bs[4][128][8];

    const u16* Ab = A + (size_t)b * NTOK * 512;

    f32x4 acc[5][2];
#pragma unroll
    for (int mt = 0; mt < 5; ++mt)
#pragma unroll
        for (int j = 0; j < 2; ++j) acc[mt][j] = (f32x4){0.f, 0.f, 0.f, 0.f};

    int rl = lane & 15, kg = lane >> 4;

    for (int k0 = 0; k0 < 512; k0 += 32) {
        for (int idx = tid; idx < 320; idx += 256) {
            int r = idx >> 2, q = idx & 3;
            int4 v = {0, 0, 0, 0};
            if (r < NTOK) v = *(const int4*)&Ab[(size_t)r * 512 + k0 + q * 8];
            *(int4*)&As[q][r][0] = v;
        }
        for (int idx = tid; idx < 512; idx += 256) {
            int c = idx & 127, kq = idx >> 7;
            u16 tmp[8];
#pragma unroll
            for (int j = 0; j < 8; ++j)
                tmp[j] = f2bf(W[(size_t)(k0 + kq * 8 + j) * N + c]);
            *(int4*)&Bs[kq][c][0] = *(int4*)tmp;
        }
        __syncthreads();
        bf16x8 bfr0 = *(const bf16x8*)&Bs[kg][(w * 2) * 16 + rl][0];
        bf16x8 bfr1 = *(const bf16x8*)&Bs[kg][(w * 2 + 1) * 16 + rl][0];
#pragma unroll
        for (int mt = 0; mt < 5; ++mt) {
            bf16x8 av = *(const bf16x8*)&As[kg][mt * 16 + rl][0];
            acc[mt][0] = __builtin_amdgcn_mfma_f32_16x16x32_bf16(av, bfr0, acc[mt][0], 0, 0, 0);
            acc[mt][1] = __builtin_amdgcn_mfma_f32_16x16x32_bf16(av, bfr1, acc[mt][1], 0, 0, 0);
        }
        __syncthreads();
    }

    int rh = lane >> 4;
#pragma unroll
    for (int mt = 0; mt < 5; ++mt)
#pragma unroll
        for (int j = 0; j < 2; ++j)
#pragma unroll
            for (int r = 0; r < 4; ++r) {
                int m = mt * 16 + rh * 4 + r;
                if (m >= NTOK) continue;
                int c = c0 + (w * 2 + j) * 16 + rl;
                float v = acc[mt][j][r];
                size_t o = ((size_t)b * NTOK + m) * N + c;
                if (OP == 0) {
                    ((u16*)Cptr)[o] = f2bf(v);
                } else if (OP == 1) {
                    float* C = (float*)Cptr;
                    C[o] += v + Bbase[(size_t)e * bestride + c];
                } else {
                    float vb = v + Bbase[(size_t)e * bestride + c];
                    float gl = vb * 0.5f * (1.f + erff(vb * 0.70710678118f));
                    ((u16*)Cptr)[o] = f2bf(gl);
                }
            }
}

// ---------------------------------------------------------------------------
// MFMA attention: block per (b,h), 4 waves. QK^T / softmax-in-reg / PV.
// LDS: Qs[80][72], Ks[80][72] (P[80][96] aliases them), Vs[65][64], Vt[64][96].
// ---------------------------------------------------------------------------
#define ATT_LDS (23040 / 2 + 8320 / 2 + 12288 / 2)  // u16 elems: Qs+Ks, Vs, Vt
__global__ __launch_bounds__(256) void attn2_k(const u16* __restrict__ qkv,
                                               u16* __restrict__ o) {
    int h = blockIdx.x, b = blockIdx.y, tid = threadIdx.x;
    __shared__ __align__(16) u16 smem[ATT_LDS];
    u16* Qs = smem;                    // [80][72]
    u16* Ks = smem + 80 * 72;          // [80][72]
    u16* Ps = smem;                    // [80][96]  (aliases Qs+Ks after barrier)
    u16* Vs = smem + 2 * 80 * 72;      // [65][64]
    u16* Vt = Vs + 65 * 64;            // [64][96]

    const u16* base = qkv + (size_t)b * NTOK * 1536 + h * 64;

    // Stage Q, K (rows >=65 zeroed), V
    for (int idx = tid; idx < 640; idx += 256) {
        int r = idx >> 3, q = idx & 7;
        int4 vq = {0, 0, 0, 0}, vk = {0, 0, 0, 0};
        if (r < NTOK) {
            vq = *(const int4*)&base[(size_t)r * 1536 + q * 8];
            vk = *(const int4*)&base[(size_t)r * 1536 + 512 + q * 8];
        }
        *(int4*)&Qs[r * 72 + q * 8] = vq;
        *(int4*)&Ks[r * 72 + q * 8] = vk;
    }
    for (int idx = tid; idx < 520; idx += 256) {
        int r = idx >> 3, q = idx & 7;
        *(int4*)&Vs[r * 64 + q * 8] = *(const int4*)&base[(size_t)r * 1536 + 1024 + q * 8];
    }
    __syncthreads();

    int lane = tid & 63, w = tid >> 6;
    int rl = lane & 15, kg = lane >> 4, g = lane >> 4;

    f32x4 acc[2][5];
#pragma unroll
    for (int mi = 0; mi < 2; ++mi)
#pragma unroll
        for (int nt = 0; nt < 5; ++nt) acc[mi][nt] = (f32x4){0.f, 0.f, 0.f, 0.f};

    // QK^T
#pragma unroll
    for (int mi = 0; mi < 2; ++mi) {
        if (mi == 1 && w != 0) continue;
        int mt = (mi == 0) ? w : 4;
        bf16x8 av0 = *(const bf16x8*)&Qs[(mt * 16 + rl) * 72 + kg * 8];
        bf16x8 av1 = *(const bf16x8*)&Qs[(mt * 16 + rl) * 72 + 32 + kg * 8];
#pragma unroll
        for (int nt = 0; nt < 5; ++nt) {
            bf16x8 bv0 = *(const bf16x8*)&Ks[(nt * 16 + rl) * 72 + kg * 8];
            bf16x8 bv1 = *(const bf16x8*)&Ks[(nt * 16 + rl) * 72 + 32 + kg * 8];
            acc[mi][nt] = __builtin_amdgcn_mfma_f32_16x16x32_bf16(av0, bv0, acc[mi][nt], 0, 0, 0);
            acc[mi][nt] = __builtin_amdgcn_mfma_f32_16x16x32_bf16(av1, bv1, acc[mi][nt], 0, 0, 0);
        }
    }

    // Transpose V -> Vt[64][96] (k >= 65 zero)
    for (int idx = tid; idx < 768; idx += 256) {
        int d = idx & 63, kq = idx >> 6;
        u16 tmp[8];
#pragma unroll
        for (int j = 0; j < 8; ++j) {
            int k = kq * 8 + j;
            tmp[j] = (k < NTOK) ? Vs[k * 64 + d] : (u16)0;
        }
        *(int4*)&Vt[d * 96 + kq * 8] = *(int4*)tmp;
    }

    // Softmax in registers: row = mt*16 + g*4 + r, col = nt*16 + rl
#pragma unroll
    for (int mi = 0; mi < 2; ++mi) {
        if (mi == 1 && w != 0) continue;
#pragma unroll
        for (int r = 0; r < 4; ++r) {
            float m = -3.0e38f;
#pragma unroll
            for (int nt = 0; nt < 5; ++nt) {
                float s = acc[mi][nt][r] * 0.125f;
                if (nt * 16 + rl >= NTOK) s = -3.0e38f;
                acc[mi][nt][r] = s;
                m = fmaxf(m, s);
            }
            m = fmaxf(m, __shfl_xor(m, 1));
            m = fmaxf(m, __shfl_xor(m, 2));
            m = fmaxf(m, __shfl_xor(m, 4));
            m = fmaxf(m, __shfl_xor(m, 8));
            float sum = 0.f;
#pragma unroll
            for (int nt = 0; nt < 5; ++nt) {
                float p = expf(acc[mi][nt][r] - m);
                acc[mi][nt][r] = p;
                sum += p;
            }
            sum += __shfl_xor(sum, 1);
            sum += __shfl_xor(sum, 2);
            sum += __shfl_xor(sum, 4);
            sum += __shfl_xor(sum, 8);
            float inv = 1.f / sum;
#pragma unroll
            for (int nt = 0; nt < 5; ++nt) acc[mi][nt][r] *= inv;
        }
    }
    __syncthreads();   // Qs/Ks dead; P may now be written

    // Write P (bf16) + zero pad cols 80..95
#pragma unroll
    for (int mi = 0; mi < 2; ++mi) {
        if (mi == 1 && w != 0) continue;
        int mt = (mi == 0) ? w : 4;
#pragma unroll
        for (int nt = 0; nt < 5; ++nt)
#pragma unroll
            for (int r = 0; r < 4; ++r)
                Ps[(mt * 16 + g * 4 + r) * 96 + nt * 16 + rl] = f2bf(acc[mi][nt][r]);
    }
    for (int idx = tid; idx < 160; idx += 256) {
        int r = idx >> 1, hf = idx & 1;
        *(int4*)&Ps[r * 96 + 80 + hf * 8] = (int4){0, 0, 0, 0};
    }
    __syncthreads();

    // PV: O[m][d] = sum_k P[m][k] * Vt[d][k], K = 96
#pragma unroll
    for (int mi = 0; mi < 2; ++mi) {
        if (mi == 1 && w != 0) continue;
        int mt = (mi == 0) ? w : 4;
#pragma unroll
        for (int dt = 0; dt < 4; ++dt) {
            f32x4 oa = {0.f, 0.f, 0.f, 0.f};
#pragma unroll
            for (int s2 = 0; s2 < 3; ++s2) {
                bf16x8 av = *(const bf16x8*)&Ps[(mt * 16 + rl) * 96 + s2 * 32 + kg * 8];
                bf16x8 bv = *(const bf16x8*)&Vt[(dt * 16 + rl) * 96 + s2 * 32 + kg * 8];
                oa = __builtin_amdgcn_mfma_f32_16x16x32_bf16(av, bv, oa, 0, 0, 0);
            }
#pragma unroll
            for (int r = 0; r < 4; ++r) {
                int row = mt * 16 + g * 4 + r;
                if (row < NTOK)
                    o[((size_t)b * NTOK + row) * DIM + h * 64 + dt * 16 + rl] = f2bf(oa[r]);
            }
        }
    }
}

// ---------------------------------------------------------------------------
// Final LN (row 0) + head (fp32)
// ---------------------------------------------------------------------------
__global__ __launch_bounds__(64) void final_k(const float* __restrict__ t,
                                              const float* __restrict__ fg,
                                              const float* __restrict__ fb,
                                              const float* __restrict__ hw,
                                              const float* __restrict__ hb,
                                              const int* __restrict__ top1,
                                              float* __restrict__ out) {
    int b = blockIdx.x, lane = threadIdx.x;
    int e = top1[b];
    const float* row = t + (size_t)b * NTOK * DIM;
    float v[8], s = 0.f, q = 0.f;
#pragma unroll
    for (int ii = 0; ii < 8; ++ii) {
        v[ii] = row[ii * 64 + lane];
        s += v[ii];
        q += v[ii] * v[ii];
    }
    for (int off = 32; off > 0; off >>= 1) {
        s += __shfl_xor(s, off);
        q += __shfl_xor(q, off);
    }
    float mean = s * (1.f / DIM);
    float var = q * (1.f / DIM) - mean * mean;
    float rs = rsqrtf(var + 1e-5f);
    float nv[8];
#pragma unroll
    for (int ii = 0; ii < 8; ++ii) {
        int d = ii * 64 + lane;
        nv[ii] = (v[ii] - mean) * rs * fg[e * DIM + d] + fb[e * DIM + d];
    }
    for (int c = 0; c < NCLS; ++c) {
        float p = 0.f;
#pragma unroll
        for (int ii = 0; ii < 8; ++ii) {
            int d = ii * 64 + lane;
            p = fmaf(nv[ii], hw[(size_t)e * DIM * NCLS + d * NCLS + c], p);
        }
        for (int off = 32; off > 0; off >>= 1) p += __shfl_xor(p, off);
        if (lane == 0) out[b * NCLS + c] = p + hb[e * NCLS + c];
    }
}

// ---------------------------------------------------------------------------
extern "C" void kernel_launch(void* const* d_in, const int* in_sizes, int n_in,
                              void* d_out, int out_size, void* d_ws, size_t ws_size,
                              hipStream_t stream) {
    const float* x       = (const float*)d_in[0];
    const float* gate_w  = (const float*)d_in[1];
    const float* gate_b  = (const float*)d_in[2];
    const float* pln1_g  = (const float*)d_in[3];
    const float* pln1_b  = (const float*)d_in[4];
    const float* patch_w = (const float*)d_in[5];
    const float* patch_b = (const float*)d_in[6];
    const float* pln2_g  = (const float*)d_in[7];
    const float* pln2_b  = (const float*)d_in[8];
    const float* cls_tok = (const float*)d_in[9];
    const float* pos_emb = (const float*)d_in[10];
    const float* aln_g   = (const float*)d_in[11];
    const float* aln_b   = (const float*)d_in[12];
    const float* qkv_w   = (const float*)d_in[13];
    const float* out_w   = (const float*)d_in[14];
    const float* out_b   = (const float*)d_in[15];
    const float* fln_g   = (const float*)d_in[16];
    const float* fln_b   = (const float*)d_in[17];
    const float* ff1_w   = (const float*)d_in[18];
    const float* ff1_b   = (const float*)d_in[19];
    const float* ff2_w   = (const float*)d_in[20];
    const float* ff2_b   = (const float*)d_in[21];
    const float* final_g = (const float*)d_in[22];
    const float* final_b = (const float*)d_in[23];
    const float* head_w  = (const float*)d_in[24];
    const float* head_b  = (const float*)d_in[25];
    float* out = (float*)d_out;

    // Workspace layout
    int* top1 = (int*)d_ws;
    float* t  = (float*)((char*)d_ws + 1024);                // fp32 [B,65,512]
    u16* g16  = (u16*)(t + (size_t)BATCH * NTOK * DIM);      // bf16 [B,65,512]
    u16* qb16 = g16 + (size_t)BATCH * NTOK * DIM;            // bf16 [B,65,1536]
    u16* wq_t = qb16 + (size_t)BATCH * NTOK * 1536;          // bf16 [48][1536][512]
    u16* wo_t = wq_t + (size_t)48 * 1536 * 512;              // bf16 [48][512][512]
    u16* w1_t = wo_t + (size_t)48 * 512 * 512;
    u16* w2_t = w1_t + (size_t)48 * 512 * 512;

    size_t need = 1024 + (size_t)BATCH * NTOK * DIM * 4 + (size_t)BATCH * NTOK * DIM * 2 +
                  (size_t)BATCH * NTOK * 1536 * 2 +
                  (size_t)48 * 1536 * 512 * 2 + 3 * (size_t)48 * 512 * 512 * 2;
    bool preconv = ws_size >= need;

    gate_k<<<BATCH, 256, 0, stream>>>(x, gate_w, gate_b, top1);
    patch_k<<<dim3(NTOK, BATCH), 256, 0, stream>>>(x, pln1_g, pln1_b, patch_w, patch_b,
                                                   pln2_g, pln2_b, cls_tok, pos_emb, top1, t);
    if (preconv) {
        wconv_k<<<dim3(48, 16, 48), 256, 0, stream>>>(qkv_w, wq_t, 1536);
        wconv_k<<<dim3(16, 16, 48), 256, 0, stream>>>(out_w, wo_t, 512);
        wconv_k<<<dim3(16, 16, 48), 256, 0, stream>>>(ff1_w, w1_t, 512);
        wconv_k<<<dim3(16, 16, 48), 256, 0, stream>>>(ff2_w, w2_t, 512);
    }

    for (int l = 0; l < DEPTH; ++l) {
        ln_k<<<dim3(NTOK, BATCH), 256, 0, stream>>>(t, g16, aln_g + l * DIM, aln_b + l * DIM,
                                                    top1, DEPTH * DIM);
        if (preconv)
            mgemm2_k<1536, 0><<<dim3(12, BATCH), 256, 0, stream>>>(
                g16, wq_t + (size_t)l * 1536 * 512, nullptr, qb16, top1,
                DEPTH * 512 * 1536, 0);
        else
            mgemm_k<1536, 0><<<dim3(12, BATCH), 256, 0, stream>>>(
                g16, qkv_w + (size_t)l * 512 * 1536, nullptr, qb16, top1,
                DEPTH * 512 * 1536, 0);
        attn2_k<<<dim3(HEADS, BATCH), 256, 0, stream>>>(qb16, g16);
        if (preconv) {
            mgemm2_k<512, 1><<<dim3(4, BATCH), 256, 0, stream>>>(
                g16, wo_t + (size_t)l * 512 * 512, out_b + l * DIM, t, top1,
                DEPTH * 512 * 512, DEPTH * DIM);
        } else {
            mgemm_k<512, 1><<<dim3(4, BATCH), 256, 0, stream>>>(
                g16, out_w + (size_t)l * 512 * 512, out_b + l * DIM, t, top1,
                DEPTH * 512 * 512, DEPTH * DIM);
        }
        ln_k<<<dim3(NTOK, BATCH), 256, 0, stream>>>(t, g16, fln_g + l * DIM, fln_b + l * DIM,
                                                    top1, DEPTH * DIM);
        if (preconv) {
            mgemm2_k<512, 2><<<dim3(4, BATCH), 256, 0, stream>>>(
                g16, w1_t + (size_t)l * 512 * 512, ff1_b + l * DIM, qb16, top1,
                DEPTH * 512 * 512, DEPTH * DIM);
            mgemm2_k<512, 1><<<dim3(4, BATCH), 256, 0, stream>>>(
                qb16, w2_t + (size_t)l * 512 * 512, ff2_b + l * DIM, t, top1,
                DEPTH * 512 * 512, DEPTH * DIM);
        } else {
            mgemm_k<512, 2><<<dim3(4, BATCH), 256, 0, stream>>>(
                g16, ff1_w + (size_t)l * 512 * 512, ff1_b + l * DIM, qb16, top1,
                DEPTH * 512 * 512, DEPTH * DIM);
            mgemm_k<512, 1><<<dim3(4, BATCH), 256, 0, stream>>>(
                qb16, ff2_w + (size_t)l * 512 * 512, ff2_b + l * DIM, t, top1,
                DEPTH * 512 * 512, DEPTH * DIM);
        }
    }
    final_k<<<BATCH, 64, 0, stream>>>(t, final_g, final_b, head_w, head_b, top1, out);
}